// Round 11
// baseline (283.743 us; speedup 1.0000x reference)
//
#include <hip/hip_runtime.h>
#include <stdint.h>

typedef unsigned short u16;
typedef __attribute__((ext_vector_type(8))) short bf16x8;
typedef __attribute__((ext_vector_type(4))) float f32x4;
typedef __attribute__((ext_vector_type(4))) unsigned short us4;

#define ND 6000
#define NT 12000
#define HD 256
#define NCH 8
#define CHW 750
#define LDH 136   // LDS candidate stride (shorts); 272 B rows, 16B-divisible

__device__ __forceinline__ float bf2f(unsigned int u) {
  u = (u & 0xffffu) << 16;
  return __builtin_bit_cast(float, u);
}
__device__ __forceinline__ u16 f2bf(float f) {
  unsigned int x = __builtin_bit_cast(unsigned int, f);
  x += 0x7fffu + ((x >> 16) & 1u);          // round-to-nearest-even
  return (u16)(x >> 16);
}

// fused prep (self-detecting dtype). grid 3065:
//   b in [0,3000):  per-row norms (wave == row): rinv (f32 proxy scale) + rinv64
//                   (f64, k_rank). ce copy ONLY when f32 input (bf16 inputs are
//                   read directly by k_simxw -- no copy).
//   b in [3000,3064): canon gw -> cgwh
//   b == 3064:      params
// NOTE: sim operands stay RAW bf16 (r2/r3 lesson: never re-quantize).
// NOTE: k_rank re-rank must stay f64 (r9 lesson: f32 dot error ~1e-6 vs near-tie
// gap tail -> ~7 flipped nodes at 12000 trials; absmax 0.209 failure).
__global__ __launch_bounds__(256) void k_prep(const void* __restrict__ e0, const void* __restrict__ e1,
                                              const void* __restrict__ gw, const void* __restrict__ gb,
                                              const void* __restrict__ aw, const void* __restrict__ ab,
                                              u16* __restrict__ ce, u16* __restrict__ cgwh,
                                              float* __restrict__ pgb, float* __restrict__ paw,
                                              float* __restrict__ pab, float* __restrict__ rinv,
                                              double* __restrict__ rinv64,
                                              int* __restrict__ cnt, int* __restrict__ fill,
                                              float* __restrict__ macc, int* __restrict__ flag) {
  const int b = blockIdx.x, tid = threadIdx.x;
  // --- self-detect dtype: f32 data read as bf16 low-halves has wild magnitudes ---
  uint2 du = ((const uint2*)e0)[tid];
  float dv0 = bf2f(du.x), dv2 = bf2f(du.y);
  int big = (!(fabsf(dv0) <= 1024.0f)) || (!(fabsf(dv2) <= 1024.0f));
  const int isf32 = __syncthreads_or(big);
  if (b == 0 && tid == 0) flag[0] = isf32;   // for k_simxw / k_rank / k_gather / k_loss

  if (b < 3000) {                      // embeddings: norms (+ copy only if f32)
    int i = b * 256 + tid;             // elements [i*4, i*4+4) of row node = i>>6
    const void* src; int li;
    if (i < 384000) { src = e0; li = i; } else { src = e1; li = i - 384000; }
    float f0, f1, f2, f3;
    if (isf32) {
      float4 v = ((const float4*)src)[li];
      f0 = v.x; f1 = v.y; f2 = v.z; f3 = v.w;
      us4 h;
      h[0] = f2bf(v.x); h[1] = f2bf(v.y); h[2] = f2bf(v.z); h[3] = f2bf(v.w);
      *(us4*)(ce + (size_t)i * 4) = h;
    } else {
      us4 h = ((const us4*)src)[li];
      f0 = bf2f(h[0]); f1 = bf2f(h[1]); f2 = bf2f(h[2]); f3 = bf2f(h[3]);
    }
    // per-row norm: each wave (64 lanes) == one row of 256 elems
    double s = (double)f0 * f0 + (double)f1 * f1 + (double)f2 * f2 + (double)f3 * f3;
    #pragma unroll
    for (int off = 32; off > 0; off >>= 1) s += __shfl_xor(s, off);
    if ((tid & 63) == 0) {
      double rd = 1.0 / fmax(sqrt(s), 1e-12);
      int node = i >> 6;
      rinv[node] = (float)rd;
      rinv64[node] = rd;
    }
    if (b < 47) {                      // init fold
      int k = b * 256 + tid;
      if (k < NT) { cnt[k] = 0; fill[k] = 0; }
      if (k < 512) macc[k] = 0.0f;
    }
  } else if (b < 3064) {               // gnn_weight: 65536 elems
    int i = (b - 3000) * 256 + tid;
    us4 h;
    if (isf32) {
      float4 v = ((const float4*)gw)[i];
      h[0] = f2bf(v.x); h[1] = f2bf(v.y); h[2] = f2bf(v.z); h[3] = f2bf(v.w);
    } else {
      h = ((const us4*)gw)[i];
    }
    *(us4*)(cgwh + (size_t)i * 4) = h;
  } else {                             // params
    if (isf32) {
      pgb[tid] = ((const float*)gb)[tid];
      paw[tid] = ((const float*)aw)[tid];
      if (tid == 0) pab[0] = ((const float*)ab)[0];
    } else {
      pgb[tid] = bf2f(((const u16*)gb)[tid]);
      paw[tid] = bf2f(((const u16*)aw)[tid]);
      if (tid == 0) pab[0] = bf2f(((const u16*)ab)[0]);
    }
  }
}

// FUSED sim + xw. grid 2256 = 1504 sim blocks + 752 xw blocks (r8-proven fusion:
// xw rides in sim's spare wave slots, ~free). bf16 inputs are read DIRECTLY from
// e0/e1; f32 inputs go through the ce copy.
// r11: DOUBLE-BUFFERED LDS staging -- 1 barrier per half (24/block, was 48) and
// the next half's global-load latency overlaps the current half's MFMAs. Buffer
// parity is static: half0 -> buf0, half1 -> buf1. Numerics identical to r10.
__global__ __launch_bounds__(256) void k_simxw(const void* __restrict__ e0raw, const void* __restrict__ e1raw,
                                               const u16* __restrict__ ce, const float* __restrict__ rinv,
                                               const u16* __restrict__ gwh, const int* __restrict__ flag,
                                               unsigned int* __restrict__ kbuf, u16* __restrict__ xwb) {
  __shared__ __align__(16) short ldsC[2][64 * LDH];   // 34816 B (sim path only)
  const int bx = blockIdx.x;
  const int tid = threadIdx.x, w = tid >> 6, l = tid & 63;
  const int l15 = l & 15, lq = l >> 4;
  const int isf32 = flag[0];

  if (bx >= 1504) {
    // ---------------- xw path ----------------
    int b2 = bx - 1504;
    int mblk = b2 % 188, hy = b2 / 188;
    int m0 = mblk * 64 + w * 16 + l15;
    int mc = (m0 < NT) ? m0 : NT - 1;
    const u16* arow;
    if (isf32) arow = ce + (size_t)mc * HD;
    else if (mc < ND) arow = (const u16*)e0raw + (size_t)mc * HD;
    else arow = (const u16*)e1raw + (size_t)(mc - ND) * HD;
    bf16x8 afr[8];
    #pragma unroll
    for (int ks = 0; ks < 8; ++ks) afr[ks] = *(const bf16x8*)(arow + ks * 32 + lq * 8);
    int hbase = hy * 64;
    for (int ct = 0; ct < 4; ++ct) {
      f32x4 acc = {0.f, 0.f, 0.f, 0.f};
      const u16* brow = gwh + (size_t)(hbase + ct * 16 + l15) * HD;
      #pragma unroll
      for (int ks = 0; ks < 8; ++ks) {
        bf16x8 b = *(const bf16x8*)(brow + ks * 32 + lq * 8);
        acc = __builtin_amdgcn_mfma_f32_16x16x32_bf16(afr[ks], b, acc, 0, 0, 0);
      }
      #pragma unroll
      for (int r = 0; r < 4; ++r) {
        int m = mblk * 64 + w * 16 + lq * 4 + r;
        if (m < NT) xwb[(size_t)m * HD + hbase + ct * 16 + l15] = f2bf(acc[r]);
      }
    }
    return;
  }

  // ---------------- sim path ----------------
  const int x = bx % 94;
  const int y = (bx / 94) % NCH;
  const int pass = bx / (94 * NCH);
  const int crow0 = pass ? 0 : ND;
  const int qbase = x * 64;
  const int cch = y * CHW;
  const int cend = (cch + CHW < ND) ? cch + CHW : ND;   // == cch+750 (8*750 = 6000 exactly)

  // domain-local bases: queries pass0=e0/pass1=e1; candidates pass0=e1/pass1=e0
  const u16* Qb = isf32 ? (ce + (size_t)(pass ? ND : 0) * HD)
                        : (const u16*)(pass ? e1raw : e0raw);
  const u16* C  = isf32 ? (ce + (size_t)crow0 * HD)
                        : (const u16*)(pass ? e0raw : e1raw);

  int ql = qbase + w * 16 + l15; if (ql > ND - 1) ql = ND - 1;
  const u16* qh = Qb + (size_t)ql * HD;
  bf16x8 afh[8];
  #pragma unroll
  for (int kk = 0; kk < 8; ++kk) afh[kk] = *(const bf16x8*)(qh + kk * 32 + lq * 8);

  // packed-key top-8, sorted descending; 0 == empty-or-nonpositive.
  // Key = positive-score bits (upper 22) | 10-bit chunk-local idx. Safe: final
  // edges require sim>0 and every row has ~3000 positive candidates.
  unsigned int tv[8];
  #pragma unroll
  for (int k = 0; k < 8; ++k) tv[k] = 0u;

  // stage half kh (128 cols) of the 64-row tile at c0 into buffer buf
  auto STAGE = [&](int c0, int kh, int buf) {
    #pragma unroll
    for (int sw = 0; sw < 4; ++sw) {
      int flat = (sw * 256 + tid) * 8;
      int r = flat >> 7, col = flat & 127;
      int cr = c0 + r; if (cr > cend - 1) cr = cend - 1;
      *(int4*)&ldsC[buf][r * LDH + col] = *(const int4*)(C + (size_t)cr * HD + kh * 128 + col);
    }
  };

  STAGE(cch, 0, 0);                       // prologue: tile0 half0 -> buf0

  for (int tile = 0; tile < 12; ++tile) { // 12 tiles of 64 cover CHW=750
    const int c0 = cch + tile * 64;
    f32x4 acc[4];
    #pragma unroll
    for (int ct = 0; ct < 4; ++ct) acc[ct] = (f32x4){0.f, 0.f, 0.f, 0.f};

    __syncthreads();                      // buf0(this half) written; buf1 free
    STAGE(c0, 1, 1);                      // prefetch half1 while computing half0
    #pragma unroll
    for (int ks = 0; ks < 4; ++ks) {
      #pragma unroll
      for (int ct = 0; ct < 4; ++ct) {
        bf16x8 bh = *(const bf16x8*)&ldsC[0][(ct * 16 + l15) * LDH + ks * 32 + lq * 8];
        // swapped: A = candidates (rows -> lq*4+r), B = queries (col -> l15)
        acc[ct] = __builtin_amdgcn_mfma_f32_16x16x32_bf16(bh, afh[ks], acc[ct], 0, 0, 0);
      }
    }

    __syncthreads();                      // buf1 written; buf0 free
    if (tile + 1 < 12) STAGE(c0 + 64, 0, 0);  // prefetch next tile half0
    #pragma unroll
    for (int ks = 0; ks < 4; ++ks) {
      #pragma unroll
      for (int ct = 0; ct < 4; ++ct) {
        bf16x8 bh = *(const bf16x8*)&ldsC[1][(ct * 16 + l15) * LDH + ks * 32 + lq * 8];
        acc[ct] = __builtin_amdgcn_mfma_f32_16x16x32_bf16(bh, afh[4 + ks], acc[ct], 0, 0, 0);
      }
    }

    // ---- in-register epilogue (no LDS): scale by cand rinv, pack, CE insert ----
    const float* rbase = rinv + crow0 + c0 + lq * 4;
    const int lim = cend - c0;                 // < 64 only on tile 11 (46 rows)
    const int cl0 = (c0 - cch) + lq * 4;       // chunk-local id (fits 10 bits: < 750)
    if (lim >= 64) {
      #pragma unroll
      for (int ct = 0; ct < 4; ++ct) {
        float4 rc = *(const float4*)(rbase + ct * 16);
        float rcv[4] = {rc.x, rc.y, rc.z, rc.w};
        #pragma unroll
        for (int r = 0; r < 4; ++r) {
          float xx = acc[ct][r] * rcv[r];
          unsigned int u = __builtin_bit_cast(unsigned int, xx);
          unsigned int key = (xx > 0.0f)
              ? ((u & 0xFFFFFC00u) | (unsigned int)(cl0 + ct * 16 + r)) : 0u;
          #pragma unroll
          for (int k = 0; k < 8; ++k) {        // branchless compare-exchange insert
            unsigned int hi = key > tv[k] ? key : tv[k];
            key = key > tv[k] ? tv[k] : key;
            tv[k] = hi;
          }
        }
      }
    } else {
      #pragma unroll
      for (int ct = 0; ct < 4; ++ct) {
        float4 rc = *(const float4*)(rbase + ct * 16);
        float rcv[4] = {rc.x, rc.y, rc.z, rc.w};
        #pragma unroll
        for (int r = 0; r < 4; ++r) {
          int cl64 = ct * 16 + lq * 4 + r;
          float xx = acc[ct][r] * rcv[r];
          unsigned int u = __builtin_bit_cast(unsigned int, xx);
          unsigned int key = (cl64 < lim && xx > 0.0f)
              ? ((u & 0xFFFFFC00u) | (unsigned int)(cl0 + ct * 16 + r)) : 0u;
          #pragma unroll
          for (int k = 0; k < 8; ++k) {
            unsigned int hi = key > tv[k] ? key : tv[k];
            key = key > tv[k] ? tv[k] : key;
            tv[k] = hi;
          }
        }
      }
    }
  }

  // merge the 4 per-lane-group lists per query row -> per-chunk top-8 packed keys
  __syncthreads();                             // all buffer reads done before overlay
  unsigned int* ldsK = (unsigned int*)ldsC;    // 256*9*4 = 9216 B, fits in buf0
  #pragma unroll
  for (int k = 0; k < 8; ++k) ldsK[tid * 9 + k] = tv[k];   // stride 9: conflict-free
  __syncthreads();
  if (tid < 64) {
    int qrow = qbase + tid;
    if (qrow < ND) {
      unsigned int mv[8];
      #pragma unroll
      for (int k = 0; k < 8; ++k) mv[k] = 0u;
      for (int q = 0; q < 4; ++q) {
        int src = (tid >> 4) * 64 + q * 16 + (tid & 15);   // quarter q of row tid
        #pragma unroll
        for (int k = 0; k < 8; ++k) {
          unsigned int xk = ldsK[src * 9 + k];
          #pragma unroll
          for (int kk = 0; kk < 8; ++kk) {
            unsigned int hi = xk > mv[kk] ? xk : mv[kk];
            xk = xk > mv[kk] ? mv[kk] : xk;
            mv[kk] = hi;
          }
        }
      }
      size_t base = ((size_t)(pass * ND + qrow) * NCH + y) * 8;
      #pragma unroll
      for (int k = 0; k < 8; ++k) kbuf[base + k] = mv[k];
    }
  }
}

// fused merge + exact re-rank. One wave per node. Phase A: coalesced packed-key
// load + 12 wave-argmax rounds. Phase B: f64 dot butterfly per candidate (f64 is
// REQUIRED -- r9's f32 attempt flipped ~7 near-tie nodes, absmax 0.209), scale by
// precomputed rinv64, lane-0 top-5, emit edges.
__global__ __launch_bounds__(256) void k_rank(const void* __restrict__ e0raw, const void* __restrict__ e1raw,
                                              const unsigned int* __restrict__ kbuf,
                                              const double* __restrict__ rinv64,
                                              const int* __restrict__ flag,
                                              int* __restrict__ edst, int* __restrict__ cnt) {
  int tid = threadIdx.x, w = tid >> 6, l = tid & 63;
  int n = blockIdx.x * 4 + w;
  const int isf32 = flag[0];
  int pass = (n >= ND) ? 1 : 0;
  int crow0 = pass ? 0 : ND;

  // ---- phase A: top-12 of the 64 per-chunk keys ----
  unsigned int key = kbuf[(size_t)n * 64 + l];
  int cids[12];
  #pragma unroll
  for (int r = 0; r < 12; ++r) {
    unsigned int m = key;
    #pragma unroll
    for (int off = 32; off > 0; off >>= 1) {
      unsigned int o = __shfl_xor(m, off);
      m = (o > m) ? o : m;
    }
    int cid = -1;
    if (m != 0u) {
      unsigned long long b = __ballot(key == m);
      int wl = __ffsll(b) - 1;                 // first lane holding the max
      cid = crow0 + (wl >> 3) * CHW + (int)(m & 1023u);
      if (l == wl) key = 0u;                   // remove winner, keep duplicates
    }
    cids[r] = cid;
  }

  // ---- phase B: exact f64 re-rank ----
  int qloc = (n < ND) ? n : n - ND;
  const void* qb = (n < ND) ? e0raw : e1raw;
  double q0, q1, q2, q3;
  if (isf32) {
    float4 v = *(const float4*)((const float*)qb + (size_t)qloc * HD + l * 4);
    q0 = v.x; q1 = v.y; q2 = v.z; q3 = v.w;
  } else {
    us4 v = *(const us4*)((const u16*)qb + (size_t)qloc * HD + l * 4);
    q0 = bf2f(v[0]); q1 = bf2f(v[1]); q2 = bf2f(v[2]); q3 = bf2f(v[3]);
  }
  double dv[12];
  #pragma unroll
  for (int c = 0; c < 12; ++c) {
    int cid = cids[c];
    int cidc = (cid < 0) ? 0 : cid;
    int cloc = (cidc < ND) ? cidc : cidc - ND;
    const void* cb = (cidc < ND) ? e0raw : e1raw;
    double c0, c1, c2, c3;
    if (isf32) {
      float4 v = *(const float4*)((const float*)cb + (size_t)cloc * HD + l * 4);
      c0 = v.x; c1 = v.y; c2 = v.z; c3 = v.w;
    } else {
      us4 v = *(const us4*)((const u16*)cb + (size_t)cloc * HD + l * 4);
      c0 = bf2f(v[0]); c1 = bf2f(v[1]); c2 = bf2f(v[2]); c3 = bf2f(v[3]);
    }
    double dot = q0 * c0 + q1 * c1 + q2 * c2 + q3 * c3;
    #pragma unroll
    for (int off = 32; off > 0; off >>= 1) dot += __shfl_xor(dot, off);
    double rv = rinv64[cidc];
    dv[c] = (cid < 0) ? -1e300 : dot * rv;   // rv > 0: sign(dv) == sign(dot)
  }
  if (l == 0) {
    double tv5[5]; int ti5[5];
    #pragma unroll
    for (int k = 0; k < 5; ++k) { tv5[k] = -1e300; ti5[k] = -1; }
    #pragma unroll
    for (int c = 0; c < 12; ++c) {
      double x = dv[c]; int id = cids[c];
      #pragma unroll
      for (int k = 0; k < 5; ++k) {
        if (x > tv5[k]) { double ov = tv5[k]; int oi = ti5[k]; tv5[k] = x; ti5[k] = id; x = ov; id = oi; }
      }
    }
    #pragma unroll
    for (int k = 0; k < 5; ++k) {
      // reference: masked zeros beat negative sims -> only val>0 edges carry weight 1
      int d = (ti5[k] >= 0 && tv5[k] > 0.0) ? ti5[k] : -1;
      edst[n * 5 + k] = d;
      if (d >= 0) atomicAdd(&cnt[d], 1);
    }
  }
}

// single-block prefix scan: 12 elems/thread, wave shuffle scans, 2 barriers
__global__ __launch_bounds__(1024) void k_scan(const int* __restrict__ cnt,
                                               int* __restrict__ coff, float* __restrict__ dinv) {
  __shared__ int wsum[16];
  int tid = threadIdx.x;
  int lane = tid & 63, wv = tid >> 6;
  int base = tid * 12;
  bool act = base < NT;
  int v[12]; int s = 0;
  #pragma unroll
  for (int j = 0; j < 12; ++j) { v[j] = act ? cnt[base + j] : 0; s += v[j]; }
  int si = s;
  #pragma unroll
  for (int off = 1; off < 64; off <<= 1) { int t2 = __shfl_up(si, off); if (lane >= off) si += t2; }
  if (lane == 63) wsum[wv] = si;
  __syncthreads();
  if (wv == 0) {
    int x = (lane < 16) ? wsum[lane] : 0;
    #pragma unroll
    for (int off = 1; off < 16; off <<= 1) { int t2 = __shfl_up(x, off); if (lane >= off) x += t2; }
    if (lane < 16) wsum[lane] = x;
  }
  __syncthreads();
  int wpre = (wv > 0) ? wsum[wv - 1] : 0;
  int excl = wpre + si - s;
  if (act) {
    #pragma unroll
    for (int j = 0; j < 12; ++j) {
      coff[base + j] = excl;
      dinv[base + j] = 1.0f / sqrtf(1.0f + (float)v[j]);
      excl += v[j];
    }
  }
  if (tid == 0) coff[NT] = wsum[15];
}

__global__ __launch_bounds__(256) void k_fill(const int* __restrict__ edst, const int* __restrict__ coff,
                                              int* __restrict__ fill, int* __restrict__ cedge) {
  int s = blockIdx.x * 256 + threadIdx.x;
  if (s >= NT * 5) return;
  int d = edst[s];
  if (d < 0) return;
  int n = s / 5;
  int p = atomicAdd(&fill[d], 1);
  cedge[coff[d] + p] = n;
}

// GCN gather + attention + dtype-correct store + f32 domain-mean accumulation.
// r5/r8-proven 750-block shape (16 nodes/block).
__global__ __launch_bounds__(256) void k_gather(const void* __restrict__ e0raw, const void* __restrict__ e1raw,
                                                const u16* __restrict__ xwb, const float* __restrict__ dinv,
                                                const int* __restrict__ coff, const int* __restrict__ cedge,
                                                const float* __restrict__ pgb, const float* __restrict__ paw,
                                                const float* __restrict__ pab, const int* __restrict__ flag,
                                                void* __restrict__ outp, float* __restrict__ macc) {
  int tid = threadIdx.x, w = tid >> 6, l = tid & 63;
  const int isf32 = flag[0];
  float4 b4 = ((const float4*)pgb)[l];
  float4 a4 = ((const float4*)paw)[l];
  float ab = pab[0];
  __shared__ float bacc[256];
  bacc[tid] = 0.0f;
  __syncthreads();
  float sum0 = 0.f, sum1 = 0.f, sum2 = 0.f, sum3 = 0.f;
  int nodeBase = blockIdx.x * 16 + w * 4;
  for (int nn = 0; nn < 4; ++nn) {
    int t = nodeBase + nn;
    float dt = dinv[t];
    int o0 = coff[t], o1 = coff[t + 1];
    float g0 = 0.f, g1 = 0.f, g2 = 0.f, g3 = 0.f;
    if (o0 < o1) {
      int sc = cedge[o0];
      for (int e = o0; e < o1; ++e) {
        int sn = (e + 1 < o1) ? cedge[e + 1] : 0;   // prefetch next edge id
        float ds = dinv[sc];
        us4 xv = *(const us4*)(xwb + (size_t)sc * HD + l * 4);
        g0 += ds * bf2f(xv[0]); g1 += ds * bf2f(xv[1]);
        g2 += ds * bf2f(xv[2]); g3 += ds * bf2f(xv[3]);
        sc = sn;
      }
    }
    us4 xt = *(const us4*)(xwb + (size_t)t * HD + l * 4);
    g0 = dt * g0 + dt * dt * bf2f(xt[0]) + b4.x;
    g1 = dt * g1 + dt * dt * bf2f(xt[1]) + b4.y;
    g2 = dt * g2 + dt * dt * bf2f(xt[2]) + b4.z;
    g3 = dt * g3 + dt * dt * bf2f(xt[3]) + b4.w;
    int loc = (t < ND) ? t : t - ND;
    const void* ebase = (t < ND) ? e0raw : e1raw;
    float e4_0, e4_1, e4_2, e4_3;
    if (isf32) {
      float4 ev = *(const float4*)((const float*)ebase + (size_t)loc * HD + l * 4);
      e4_0 = ev.x; e4_1 = ev.y; e4_2 = ev.z; e4_3 = ev.w;
    } else {
      us4 ue = *(const us4*)((const u16*)ebase + (size_t)loc * HD + l * 4);
      e4_0 = bf2f(ue[0]); e4_1 = bf2f(ue[1]); e4_2 = bf2f(ue[2]); e4_3 = bf2f(ue[3]);
    }
    float s0 = e4_0 * a4.x + e4_1 * a4.y + e4_2 * a4.z + e4_3 * a4.w;
    float s1 = g0 * a4.x + g1 * a4.y + g2 * a4.z + g3 * a4.w;
    #pragma unroll
    for (int off = 32; off > 0; off >>= 1) { s0 += __shfl_xor(s0, off); s1 += __shfl_xor(s1, off); }
    s0 += ab; s1 += ab;
    float m = fmaxf(s0, s1);
    float p0 = __expf(s0 - m), p1 = __expf(s1 - m);
    float iz = 1.0f / (p0 + p1);
    float w0 = p0 * iz, w1 = p1 * iz;
    float u0 = w0 * e4_0 + w1 * g0;
    float u1 = w0 * e4_1 + w1 * g1;
    float u2 = w0 * e4_2 + w1 * g2;
    float u3 = w0 * e4_3 + w1 * g3;
    size_t ob = 1 + (size_t)t * HD + l * 4;   // out[0] = loss, hence the +1
    if (isf32) {
      float* o = (float*)outp;
      o[ob + 0] = u0; o[ob + 1] = u1; o[ob + 2] = u2; o[ob + 3] = u3;
    } else {
      u16* o = (u16*)outp;
      o[ob + 0] = f2bf(u0); o[ob + 1] = f2bf(u1); o[ob + 2] = f2bf(u2); o[ob + 3] = f2bf(u3);
    }
    sum0 += u0; sum1 += u1; sum2 += u2; sum3 += u3;
  }
  atomicAdd(&bacc[l * 4 + 0], sum0);
  atomicAdd(&bacc[l * 4 + 1], sum1);
  atomicAdd(&bacc[l * 4 + 2], sum2);
  atomicAdd(&bacc[l * 4 + 3], sum3);
  __syncthreads();
  int dom = (blockIdx.x < 375) ? 0 : 1;   // 16 nodes/block, 375 blocks/domain: never straddles
  atomicAdd(&macc[dom * 256 + tid], bacc[tid]);
}

__global__ __launch_bounds__(256) void k_loss(const float* __restrict__ macc, const int* __restrict__ flag,
                                              void* __restrict__ outp) {
  int tid = threadIdx.x;
  float d = (macc[tid] - macc[256 + tid]) * (1.0f / (float)ND);
  float v = d * d;
  #pragma unroll
  for (int off = 32; off > 0; off >>= 1) v += __shfl_xor(v, off);
  __shared__ float rr[4];
  if ((tid & 63) == 0) rr[tid >> 6] = v;
  __syncthreads();
  if (tid == 0) {
    float loss = rr[0] + rr[1] + rr[2] + rr[3];
    if (flag[0]) ((float*)outp)[0] = loss;
    else ((u16*)outp)[0] = f2bf(loss);
  }
}

extern "C" void kernel_launch(void* const* d_in, const int* in_sizes, int n_in,
                              void* d_out, int out_size, void* d_ws, size_t ws_size,
                              hipStream_t stream) {
  const void* e0 = d_in[2];    // src_embedding_0 (6000x256)
  const void* e1 = d_in[3];    // src_embedding_1
  const void* gw = d_in[8];    // gnn_weight (256x256)
  const void* gb = d_in[9];    // gnn_bias (256)
  const void* aw = d_in[10];   // attn_weight (256)
  const void* abp = d_in[11];  // attn_bias (1)

  float* wsf = (float*)d_ws;   // offsets in 4-byte slots
  size_t o = 0;
  int*    flag  = (int*)(wsf + o); o += 4;
  u16*    ce    = (u16*)(wsf + o); o += 1536000;   // 12000x256 bf16 (written/used only for f32 inputs)
  u16*    cgwh  = (u16*)(wsf + o); o += 32768;     // 256x256 bf16
  float*  pgb   = wsf + o; o += 256;
  float*  paw   = wsf + o; o += 256;
  float*  pab   = wsf + o; o += 8;
  double* rinv64 = (double*)(wsf + o); o += 24000; // 12000 f64 (offset even -> 8B aligned)
  float*  rinv  = wsf + o; o += 12032;
  unsigned int* kbuf = (unsigned int*)(wsf + o); o += 768000;  // 12000 x 8ch x 8 packed keys
  u16*    xwb   = (u16*)(wsf + o); o += 1536000;   // 12000x256 bf16 -- SEPARATE (fused kernel
                                                   // writes kbuf and xwb concurrently; no overlay)
  int*    edst  = (int*)(wsf + o); o += 60000;
  int*    cnt   = (int*)(wsf + o); o += 12000;
  int*    fill  = (int*)(wsf + o); o += 12000;
  int*    coff  = (int*)(wsf + o); o += 12008;
  int*    cedge = (int*)(wsf + o); o += 60000;
  float*  macc  = wsf + o; o += 512;
  float*  dinv  = wsf + o; o += 12000;             // total ~16.3 MiB (<= r4's proven-live 18.9 MiB)
  (void)in_sizes; (void)n_in; (void)out_size; (void)ws_size;

  k_prep<<<3065, 256, 0, stream>>>(e0, e1, gw, gb, aw, abp, ce, cgwh, pgb, paw, pab,
                                   rinv, rinv64, cnt, fill, macc, flag);
  k_simxw<<<2256, 256, 0, stream>>>(e0, e1, ce, rinv, cgwh, flag, kbuf, xwb);
  k_rank<<<3000, 256, 0, stream>>>(e0, e1, kbuf, rinv64, flag, edst, cnt);
  k_scan<<<1, 1024, 0, stream>>>(cnt, coff, dinv);
  k_fill<<<235, 256, 0, stream>>>(edst, coff, fill, cedge);
  k_gather<<<750, 256, 0, stream>>>(e0, e1, xwb, dinv, coff, cedge, pgb, paw, pab, flag, d_out, macc);
  k_loss<<<1, 256, 0, stream>>>(macc, flag, d_out);
}

// Round 13
// 274.323 us; speedup vs baseline: 1.0343x; 1.0343x over previous
//
#include <hip/hip_runtime.h>
#include <stdint.h>

typedef unsigned short u16;
typedef __attribute__((ext_vector_type(8))) short bf16x8;
typedef __attribute__((ext_vector_type(4))) float f32x4;
typedef __attribute__((ext_vector_type(4))) unsigned short us4;

#define ND 6000
#define NT 12000
#define HD 256
#define NCH 8
#define CHW 750
#define LDH 136   // LDS candidate stride (shorts); 272 B rows, 16B-divisible

__device__ __forceinline__ float bf2f(unsigned int u) {
  u = (u & 0xffffu) << 16;
  return __builtin_bit_cast(float, u);
}
__device__ __forceinline__ u16 f2bf(float f) {
  unsigned int x = __builtin_bit_cast(unsigned int, f);
  x += 0x7fffu + ((x >> 16) & 1u);          // round-to-nearest-even
  return (u16)(x >> 16);
}

// fused prep (self-detecting dtype). grid 3065:
//   b in [0,3000):  per-row norms (wave == row): rinv (f32 proxy scale) + rinv64
//                   (f64, k_rank). ce copy ONLY when f32 input (bf16 inputs are
//                   read directly by k_simxw -- no copy).
//   b in [3000,3064): canon gw -> cgwh
//   b == 3064:      params
// NOTE: sim operands stay RAW bf16 (r2/r3 lesson: never re-quantize).
// NOTE: k_rank re-rank must stay f64 (r9 lesson: f32 dot error ~1e-6 vs near-tie
// gap tail -> ~7 flipped nodes at 12000 trials; absmax 0.209 failure).
__global__ __launch_bounds__(256) void k_prep(const void* __restrict__ e0, const void* __restrict__ e1,
                                              const void* __restrict__ gw, const void* __restrict__ gb,
                                              const void* __restrict__ aw, const void* __restrict__ ab,
                                              u16* __restrict__ ce, u16* __restrict__ cgwh,
                                              float* __restrict__ pgb, float* __restrict__ paw,
                                              float* __restrict__ pab, float* __restrict__ rinv,
                                              double* __restrict__ rinv64,
                                              int* __restrict__ cnt, int* __restrict__ fill,
                                              float* __restrict__ macc, int* __restrict__ flag) {
  const int b = blockIdx.x, tid = threadIdx.x;
  // --- self-detect dtype: f32 data read as bf16 low-halves has wild magnitudes ---
  uint2 du = ((const uint2*)e0)[tid];
  float dv0 = bf2f(du.x), dv2 = bf2f(du.y);
  int big = (!(fabsf(dv0) <= 1024.0f)) || (!(fabsf(dv2) <= 1024.0f));
  const int isf32 = __syncthreads_or(big);
  if (b == 0 && tid == 0) flag[0] = isf32;   // for k_simxw / k_rank / k_gather / k_loss

  if (b < 3000) {                      // embeddings: norms (+ copy only if f32)
    int i = b * 256 + tid;             // elements [i*4, i*4+4) of row node = i>>6
    const void* src; int li;
    if (i < 384000) { src = e0; li = i; } else { src = e1; li = i - 384000; }
    float f0, f1, f2, f3;
    if (isf32) {
      float4 v = ((const float4*)src)[li];
      f0 = v.x; f1 = v.y; f2 = v.z; f3 = v.w;
      us4 h;
      h[0] = f2bf(v.x); h[1] = f2bf(v.y); h[2] = f2bf(v.z); h[3] = f2bf(v.w);
      *(us4*)(ce + (size_t)i * 4) = h;
    } else {
      us4 h = ((const us4*)src)[li];
      f0 = bf2f(h[0]); f1 = bf2f(h[1]); f2 = bf2f(h[2]); f3 = bf2f(h[3]);
    }
    // per-row norm: each wave (64 lanes) == one row of 256 elems
    double s = (double)f0 * f0 + (double)f1 * f1 + (double)f2 * f2 + (double)f3 * f3;
    #pragma unroll
    for (int off = 32; off > 0; off >>= 1) s += __shfl_xor(s, off);
    if ((tid & 63) == 0) {
      double rd = 1.0 / fmax(sqrt(s), 1e-12);
      int node = i >> 6;
      rinv[node] = (float)rd;
      rinv64[node] = rd;
    }
    if (b < 47) {                      // init fold
      int k = b * 256 + tid;
      if (k < NT) { cnt[k] = 0; fill[k] = 0; }
      if (k < 512) macc[k] = 0.0f;
    }
  } else if (b < 3064) {               // gnn_weight: 65536 elems
    int i = (b - 3000) * 256 + tid;
    us4 h;
    if (isf32) {
      float4 v = ((const float4*)gw)[i];
      h[0] = f2bf(v.x); h[1] = f2bf(v.y); h[2] = f2bf(v.z); h[3] = f2bf(v.w);
    } else {
      h = ((const us4*)gw)[i];
    }
    *(us4*)(cgwh + (size_t)i * 4) = h;
  } else {                             // params
    if (isf32) {
      pgb[tid] = ((const float*)gb)[tid];
      paw[tid] = ((const float*)aw)[tid];
      if (tid == 0) pab[0] = ((const float*)ab)[0];
    } else {
      pgb[tid] = bf2f(((const u16*)gb)[tid]);
      paw[tid] = bf2f(((const u16*)aw)[tid]);
      if (tid == 0) pab[0] = bf2f(((const u16*)ab)[0]);
    }
  }
}

// FUSED sim + xw. grid 2256 = 1504 sim blocks + 752 xw blocks (r8-proven fusion:
// xw rides in sim's spare wave slots, ~free). bf16 inputs are read DIRECTLY from
// e0/e1; f32 inputs go through the ce copy. r10-proven single-buffer staging.
__global__ __launch_bounds__(256) void k_simxw(const void* __restrict__ e0raw, const void* __restrict__ e1raw,
                                               const u16* __restrict__ ce, const float* __restrict__ rinv,
                                               const u16* __restrict__ gwh, const int* __restrict__ flag,
                                               unsigned int* __restrict__ kbuf, u16* __restrict__ xwb) {
  __shared__ __align__(16) short ldsC[64 * LDH];   // 17408 B (sim path only)
  const int bx = blockIdx.x;
  const int tid = threadIdx.x, w = tid >> 6, l = tid & 63;
  const int l15 = l & 15, lq = l >> 4;
  const int isf32 = flag[0];

  if (bx >= 1504) {
    // ---------------- xw path ----------------
    int b2 = bx - 1504;
    int mblk = b2 % 188, hy = b2 / 188;
    int m0 = mblk * 64 + w * 16 + l15;
    int mc = (m0 < NT) ? m0 : NT - 1;
    const u16* arow;
    if (isf32) arow = ce + (size_t)mc * HD;
    else if (mc < ND) arow = (const u16*)e0raw + (size_t)mc * HD;
    else arow = (const u16*)e1raw + (size_t)(mc - ND) * HD;
    bf16x8 afr[8];
    #pragma unroll
    for (int ks = 0; ks < 8; ++ks) afr[ks] = *(const bf16x8*)(arow + ks * 32 + lq * 8);
    int hbase = hy * 64;
    for (int ct = 0; ct < 4; ++ct) {
      f32x4 acc = {0.f, 0.f, 0.f, 0.f};
      const u16* brow = gwh + (size_t)(hbase + ct * 16 + l15) * HD;
      #pragma unroll
      for (int ks = 0; ks < 8; ++ks) {
        bf16x8 b = *(const bf16x8*)(brow + ks * 32 + lq * 8);
        acc = __builtin_amdgcn_mfma_f32_16x16x32_bf16(afr[ks], b, acc, 0, 0, 0);
      }
      #pragma unroll
      for (int r = 0; r < 4; ++r) {
        int m = mblk * 64 + w * 16 + lq * 4 + r;
        if (m < NT) xwb[(size_t)m * HD + hbase + ct * 16 + l15] = f2bf(acc[r]);
      }
    }
    return;
  }

  // ---------------- sim path ----------------
  const int x = bx % 94;
  const int y = (bx / 94) % NCH;
  const int pass = bx / (94 * NCH);
  const int crow0 = pass ? 0 : ND;
  const int qbase = x * 64;
  const int cch = y * CHW;
  const int cend = (cch + CHW < ND) ? cch + CHW : ND;

  // domain-local bases: queries pass0=e0/pass1=e1; candidates pass0=e1/pass1=e0
  const u16* Qb = isf32 ? (ce + (size_t)(pass ? ND : 0) * HD)
                        : (const u16*)(pass ? e1raw : e0raw);
  const u16* C  = isf32 ? (ce + (size_t)crow0 * HD)
                        : (const u16*)(pass ? e0raw : e1raw);

  int ql = qbase + w * 16 + l15; if (ql > ND - 1) ql = ND - 1;
  const u16* qh = Qb + (size_t)ql * HD;
  bf16x8 afh[8];
  #pragma unroll
  for (int kk = 0; kk < 8; ++kk) afh[kk] = *(const bf16x8*)(qh + kk * 32 + lq * 8);

  // packed-key top-8, sorted descending; 0 == empty-or-nonpositive.
  // Key = positive-score bits (upper 22) | 10-bit chunk-local idx. Safe: final
  // edges require sim>0 and every row has ~3000 positive candidates.
  unsigned int tv[8];
  #pragma unroll
  for (int k = 0; k < 8; ++k) tv[k] = 0u;

  for (int c0 = cch; c0 < cend; c0 += 64) {
    f32x4 acc[4];
    #pragma unroll
    for (int ct = 0; ct < 4; ++ct) acc[ct] = (f32x4){0.f, 0.f, 0.f, 0.f};
    #pragma unroll
    for (int kh = 0; kh < 2; ++kh) {
      #pragma unroll
      for (int sw = 0; sw < 4; ++sw) {       // stage 64 rows x 128-col half (16 KB)
        int flat = (sw * 256 + tid) * 8;
        int r = flat >> 7, col = flat & 127;
        int cr = c0 + r; if (cr > cend - 1) cr = cend - 1;
        *(int4*)&ldsC[r * LDH + col] = *(const int4*)(C + (size_t)cr * HD + kh * 128 + col);
      }
      __syncthreads();
      #pragma unroll
      for (int ks = 0; ks < 4; ++ks) {
        #pragma unroll
        for (int ct = 0; ct < 4; ++ct) {
          bf16x8 bh = *(const bf16x8*)&ldsC[(ct * 16 + l15) * LDH + ks * 32 + lq * 8];
          // swapped: A = candidates (rows -> lq*4+r), B = queries (col -> l15)
          acc[ct] = __builtin_amdgcn_mfma_f32_16x16x32_bf16(bh, afh[kh * 4 + ks], acc[ct], 0, 0, 0);
        }
      }
      __syncthreads();
    }
    // ---- in-register epilogue: scale by cand rinv, pack (pos-only), CE insert ----
    const float* rbase = rinv + crow0 + c0 + lq * 4;
    const int lim = cend - c0;                 // < 64 only on each chunk's tail tile
    const int cl0 = (c0 - cch) + lq * 4;       // chunk-local id (fits 10 bits: < 750)
    if (lim >= 64) {
      #pragma unroll
      for (int ct = 0; ct < 4; ++ct) {
        float4 rc = *(const float4*)(rbase + ct * 16);
        float rcv[4] = {rc.x, rc.y, rc.z, rc.w};
        #pragma unroll
        for (int r = 0; r < 4; ++r) {
          float xx = acc[ct][r] * rcv[r];
          unsigned int u = __builtin_bit_cast(unsigned int, xx);
          unsigned int key = (xx > 0.0f)
              ? ((u & 0xFFFFFC00u) | (unsigned int)(cl0 + ct * 16 + r)) : 0u;
          #pragma unroll
          for (int k = 0; k < 8; ++k) {        // branchless compare-exchange insert
            unsigned int hi = key > tv[k] ? key : tv[k];
            key = key > tv[k] ? tv[k] : key;
            tv[k] = hi;
          }
        }
      }
    } else {
      #pragma unroll
      for (int ct = 0; ct < 4; ++ct) {
        float4 rc = *(const float4*)(rbase + ct * 16);
        float rcv[4] = {rc.x, rc.y, rc.z, rc.w};
        #pragma unroll
        for (int r = 0; r < 4; ++r) {
          int cl64 = ct * 16 + lq * 4 + r;
          float xx = acc[ct][r] * rcv[r];
          unsigned int u = __builtin_bit_cast(unsigned int, xx);
          unsigned int key = (cl64 < lim && xx > 0.0f)
              ? ((u & 0xFFFFFC00u) | (unsigned int)(cl0 + ct * 16 + r)) : 0u;
          #pragma unroll
          for (int k = 0; k < 8; ++k) {
            unsigned int hi = key > tv[k] ? key : tv[k];
            key = key > tv[k] ? tv[k] : key;
            tv[k] = hi;
          }
        }
      }
    }
  }

  // merge the 4 per-lane-group lists per query row -> per-chunk top-8 packed keys
  unsigned int* ldsK = (unsigned int*)ldsC;    // 256*9*4 = 9216 B, fits in ldsC
  #pragma unroll
  for (int k = 0; k < 8; ++k) ldsK[tid * 9 + k] = tv[k];   // stride 9: conflict-free
  __syncthreads();
  if (tid < 64) {
    int qrow = qbase + tid;
    if (qrow < ND) {
      unsigned int mv[8];
      #pragma unroll
      for (int k = 0; k < 8; ++k) mv[k] = 0u;
      for (int q = 0; q < 4; ++q) {
        int src = (tid >> 4) * 64 + q * 16 + (tid & 15);   // quarter q of row tid
        #pragma unroll
        for (int k = 0; k < 8; ++k) {
          unsigned int xk = ldsK[src * 9 + k];
          #pragma unroll
          for (int kk = 0; kk < 8; ++kk) {
            unsigned int hi = xk > mv[kk] ? xk : mv[kk];
            xk = xk > mv[kk] ? mv[kk] : xk;
            mv[kk] = hi;
          }
        }
      }
      size_t base = ((size_t)(pass * ND + qrow) * NCH + y) * 8;
      #pragma unroll
      for (int k = 0; k < 8; ++k) kbuf[base + k] = mv[k];
    }
  }
}

// fused merge + exact re-rank. One wave per node.
// Phase A: coalesced packed-key load + 12 wave-argmax rounds.
// Phase B: 4x 16-lane groups, 3 candidates each (serial depth 12->3), pure f64.
// r13 fix vs r12: the group-result gather (__shfl from lanes 16/32/48) must run
// at FULL-WAVE scope -- r12 had it inside `if (l==0)`, and ds_bpermute from
// INACTIVE lanes returns undefined data (9/12 candidates were garbage).
__global__ __launch_bounds__(256) void k_rank(const void* __restrict__ e0raw, const void* __restrict__ e1raw,
                                              const unsigned int* __restrict__ kbuf,
                                              const double* __restrict__ rinv64,
                                              const int* __restrict__ flag,
                                              int* __restrict__ edst, int* __restrict__ cnt) {
  int tid = threadIdx.x, w = tid >> 6, l = tid & 63;
  int n = blockIdx.x * 4 + w;
  const int isf32 = flag[0];
  int pass = (n >= ND) ? 1 : 0;
  int crow0 = pass ? 0 : ND;

  // ---- phase A: top-12 of the 64 per-chunk keys ----
  unsigned int key = kbuf[(size_t)n * 64 + l];
  int cids[12];
  #pragma unroll
  for (int r = 0; r < 12; ++r) {
    unsigned int m = key;
    #pragma unroll
    for (int off = 32; off > 0; off >>= 1) {
      unsigned int o = __shfl_xor(m, off);
      m = (o > m) ? o : m;
    }
    int cid = -1;
    if (m != 0u) {
      unsigned long long b = __ballot(key == m);
      int wl = __ffsll(b) - 1;                 // first lane holding the max
      cid = crow0 + (wl >> 3) * CHW + (int)(m & 1023u);
      if (l == wl) key = 0u;                   // remove winner, keep duplicates
    }
    cids[r] = cid;
  }

  // ---- phase B: exact f64 re-rank, 16-lane groups ----
  const int g = l >> 4, lg = l & 15;           // group 0..3, lane-in-group 0..15
  int qloc = (n < ND) ? n : n - ND;
  const void* qb = (n < ND) ? e0raw : e1raw;
  // lane's 16 query elems: [lg*16, lg*16+16)
  double qv[16];
  if (isf32) {
    const float* qp = (const float*)qb + (size_t)qloc * HD + lg * 16;
    #pragma unroll
    for (int c4 = 0; c4 < 4; ++c4) {
      float4 v = *(const float4*)(qp + c4 * 4);
      qv[c4 * 4 + 0] = v.x; qv[c4 * 4 + 1] = v.y; qv[c4 * 4 + 2] = v.z; qv[c4 * 4 + 3] = v.w;
    }
  } else {
    const u16* qp = (const u16*)qb + (size_t)qloc * HD + lg * 16;
    #pragma unroll
    for (int c4 = 0; c4 < 4; ++c4) {
      us4 v = *(const us4*)(qp + c4 * 4);
      qv[c4 * 4 + 0] = (double)bf2f(v[0]); qv[c4 * 4 + 1] = (double)bf2f(v[1]);
      qv[c4 * 4 + 2] = (double)bf2f(v[2]); qv[c4 * 4 + 3] = (double)bf2f(v[3]);
    }
  }
  double dvg[3];                               // this group's 3 candidate scores
  #pragma unroll
  for (int rr = 0; rr < 3; ++rr) {
    int c = rr * 4 + g;                        // candidate index 0..11
    int cid = cids[c];
    int cidc = (cid < 0) ? 0 : cid;
    int cloc = (cidc < ND) ? cidc : cidc - ND;
    const void* cb = (cidc < ND) ? e0raw : e1raw;
    double p0 = 0.0, p1 = 0.0, p2 = 0.0, p3 = 0.0;   // 4 independent chains
    if (isf32) {
      const float* cp = (const float*)cb + (size_t)cloc * HD + lg * 16;
      #pragma unroll
      for (int c4 = 0; c4 < 4; ++c4) {
        float4 v = *(const float4*)(cp + c4 * 4);
        p0 += qv[c4 * 4 + 0] * (double)v.x; p1 += qv[c4 * 4 + 1] * (double)v.y;
        p2 += qv[c4 * 4 + 2] * (double)v.z; p3 += qv[c4 * 4 + 3] * (double)v.w;
      }
    } else {
      const u16* cp = (const u16*)cb + (size_t)cloc * HD + lg * 16;
      #pragma unroll
      for (int c4 = 0; c4 < 4; ++c4) {
        us4 v = *(const us4*)(cp + c4 * 4);
        p0 += qv[c4 * 4 + 0] * (double)bf2f(v[0]); p1 += qv[c4 * 4 + 1] * (double)bf2f(v[1]);
        p2 += qv[c4 * 4 + 2] * (double)bf2f(v[2]); p3 += qv[c4 * 4 + 3] * (double)bf2f(v[3]);
      }
    }
    double dot = (p0 + p1) + (p2 + p3);
    #pragma unroll
    for (int off = 8; off > 0; off >>= 1) dot += __shfl_xor(dot, off);   // 16-lane reduce
    dvg[rr] = (cid < 0) ? -1e300 : dot * rinv64[cidc];   // rinv64 > 0: sign preserved
  }
  // gather the 12 group results -- FULL-WAVE (shuffle sources must be active)
  double dv[12];
  #pragma unroll
  for (int c = 0; c < 12; ++c) dv[c] = __shfl(dvg[c >> 2], (c & 3) * 16);
  if (l == 0) {
    double tv5[5]; int ti5[5];
    #pragma unroll
    for (int k = 0; k < 5; ++k) { tv5[k] = -1e300; ti5[k] = -1; }
    #pragma unroll
    for (int c = 0; c < 12; ++c) {
      double x = dv[c]; int id = cids[c];
      #pragma unroll
      for (int k = 0; k < 5; ++k) {
        if (x > tv5[k]) { double ov = tv5[k]; int oi = ti5[k]; tv5[k] = x; ti5[k] = id; x = ov; id = oi; }
      }
    }
    #pragma unroll
    for (int k = 0; k < 5; ++k) {
      // reference: masked zeros beat negative sims -> only val>0 edges carry weight 1
      int d = (ti5[k] >= 0 && tv5[k] > 0.0) ? ti5[k] : -1;
      edst[n * 5 + k] = d;
      if (d >= 0) atomicAdd(&cnt[d], 1);
    }
  }
}

// single-block prefix scan: 12 elems/thread, wave shuffle scans, 2 barriers
__global__ __launch_bounds__(1024) void k_scan(const int* __restrict__ cnt,
                                               int* __restrict__ coff, float* __restrict__ dinv) {
  __shared__ int wsum[16];
  int tid = threadIdx.x;
  int lane = tid & 63, wv = tid >> 6;
  int base = tid * 12;
  bool act = base < NT;
  int v[12]; int s = 0;
  #pragma unroll
  for (int j = 0; j < 12; ++j) { v[j] = act ? cnt[base + j] : 0; s += v[j]; }
  int si = s;
  #pragma unroll
  for (int off = 1; off < 64; off <<= 1) { int t2 = __shfl_up(si, off); if (lane >= off) si += t2; }
  if (lane == 63) wsum[wv] = si;
  __syncthreads();
  if (wv == 0) {
    int x = (lane < 16) ? wsum[lane] : 0;
    #pragma unroll
    for (int off = 1; off < 16; off <<= 1) { int t2 = __shfl_up(x, off); if (lane >= off) x += t2; }
    if (lane < 16) wsum[lane] = x;
  }
  __syncthreads();
  int wpre = (wv > 0) ? wsum[wv - 1] : 0;
  int excl = wpre + si - s;
  if (act) {
    #pragma unroll
    for (int j = 0; j < 12; ++j) {
      coff[base + j] = excl;
      dinv[base + j] = 1.0f / sqrtf(1.0f + (float)v[j]);
      excl += v[j];
    }
  }
  if (tid == 0) coff[NT] = wsum[15];
}

__global__ __launch_bounds__(256) void k_fill(const int* __restrict__ edst, const int* __restrict__ coff,
                                              int* __restrict__ fill, int* __restrict__ cedge) {
  int s = blockIdx.x * 256 + threadIdx.x;
  if (s >= NT * 5) return;
  int d = edst[s];
  if (d < 0) return;
  int n = s / 5;
  int p = atomicAdd(&fill[d], 1);
  cedge[coff[d] + p] = n;
}

// GCN gather + attention + dtype-correct store + f32 domain-mean accumulation.
// r5/r8-proven 750-block shape (16 nodes/block).
__global__ __launch_bounds__(256) void k_gather(const void* __restrict__ e0raw, const void* __restrict__ e1raw,
                                                const u16* __restrict__ xwb, const float* __restrict__ dinv,
                                                const int* __restrict__ coff, const int* __restrict__ cedge,
                                                const float* __restrict__ pgb, const float* __restrict__ paw,
                                                const float* __restrict__ pab, const int* __restrict__ flag,
                                                void* __restrict__ outp, float* __restrict__ macc) {
  int tid = threadIdx.x, w = tid >> 6, l = tid & 63;
  const int isf32 = flag[0];
  float4 b4 = ((const float4*)pgb)[l];
  float4 a4 = ((const float4*)paw)[l];
  float ab = pab[0];
  __shared__ float bacc[256];
  bacc[tid] = 0.0f;
  __syncthreads();
  float sum0 = 0.f, sum1 = 0.f, sum2 = 0.f, sum3 = 0.f;
  int nodeBase = blockIdx.x * 16 + w * 4;
  for (int nn = 0; nn < 4; ++nn) {
    int t = nodeBase + nn;
    float dt = dinv[t];
    int o0 = coff[t], o1 = coff[t + 1];
    float g0 = 0.f, g1 = 0.f, g2 = 0.f, g3 = 0.f;
    if (o0 < o1) {
      int sc = cedge[o0];
      for (int e = o0; e < o1; ++e) {
        int sn = (e + 1 < o1) ? cedge[e + 1] : 0;   // prefetch next edge id
        float ds = dinv[sc];
        us4 xv = *(const us4*)(xwb + (size_t)sc * HD + l * 4);
        g0 += ds * bf2f(xv[0]); g1 += ds * bf2f(xv[1]);
        g2 += ds * bf2f(xv[2]); g3 += ds * bf2f(xv[3]);
        sc = sn;
      }
    }
    us4 xt = *(const us4*)(xwb + (size_t)t * HD + l * 4);
    g0 = dt * g0 + dt * dt * bf2f(xt[0]) + b4.x;
    g1 = dt * g1 + dt * dt * bf2f(xt[1]) + b4.y;
    g2 = dt * g2 + dt * dt * bf2f(xt[2]) + b4.z;
    g3 = dt * g3 + dt * dt * bf2f(xt[3]) + b4.w;
    int loc = (t < ND) ? t : t - ND;
    const void* ebase = (t < ND) ? e0raw : e1raw;
    float e4_0, e4_1, e4_2, e4_3;
    if (isf32) {
      float4 ev = *(const float4*)((const float*)ebase + (size_t)loc * HD + l * 4);
      e4_0 = ev.x; e4_1 = ev.y; e4_2 = ev.z; e4_3 = ev.w;
    } else {
      us4 ue = *(const us4*)((const u16*)ebase + (size_t)loc * HD + l * 4);
      e4_0 = bf2f(ue[0]); e4_1 = bf2f(ue[1]); e4_2 = bf2f(ue[2]); e4_3 = bf2f(ue[3]);
    }
    float s0 = e4_0 * a4.x + e4_1 * a4.y + e4_2 * a4.z + e4_3 * a4.w;
    float s1 = g0 * a4.x + g1 * a4.y + g2 * a4.z + g3 * a4.w;
    #pragma unroll
    for (int off = 32; off > 0; off >>= 1) { s0 += __shfl_xor(s0, off); s1 += __shfl_xor(s1, off); }
    s0 += ab; s1 += ab;
    float m = fmaxf(s0, s1);
    float p0 = __expf(s0 - m), p1 = __expf(s1 - m);
    float iz = 1.0f / (p0 + p1);
    float w0 = p0 * iz, w1 = p1 * iz;
    float u0 = w0 * e4_0 + w1 * g0;
    float u1 = w0 * e4_1 + w1 * g1;
    float u2 = w0 * e4_2 + w1 * g2;
    float u3 = w0 * e4_3 + w1 * g3;
    size_t ob = 1 + (size_t)t * HD + l * 4;   // out[0] = loss, hence the +1
    if (isf32) {
      float* o = (float*)outp;
      o[ob + 0] = u0; o[ob + 1] = u1; o[ob + 2] = u2; o[ob + 3] = u3;
    } else {
      u16* o = (u16*)outp;
      o[ob + 0] = f2bf(u0); o[ob + 1] = f2bf(u1); o[ob + 2] = f2bf(u2); o[ob + 3] = f2bf(u3);
    }
    sum0 += u0; sum1 += u1; sum2 += u2; sum3 += u3;
  }
  atomicAdd(&bacc[l * 4 + 0], sum0);
  atomicAdd(&bacc[l * 4 + 1], sum1);
  atomicAdd(&bacc[l * 4 + 2], sum2);
  atomicAdd(&bacc[l * 4 + 3], sum3);
  __syncthreads();
  int dom = (blockIdx.x < 375) ? 0 : 1;   // 16 nodes/block, 375 blocks/domain: never straddles
  atomicAdd(&macc[dom * 256 + tid], bacc[tid]);
}

__global__ __launch_bounds__(256) void k_loss(const float* __restrict__ macc, const int* __restrict__ flag,
                                              void* __restrict__ outp) {
  int tid = threadIdx.x;
  float d = (macc[tid] - macc[256 + tid]) * (1.0f / (float)ND);
  float v = d * d;
  #pragma unroll
  for (int off = 32; off > 0; off >>= 1) v += __shfl_xor(v, off);
  __shared__ float rr[4];
  if ((tid & 63) == 0) rr[tid >> 6] = v;
  __syncthreads();
  if (tid == 0) {
    float loss = rr[0] + rr[1] + rr[2] + rr[3];
    if (flag[0]) ((float*)outp)[0] = loss;
    else ((u16*)outp)[0] = f2bf(loss);
  }
}

extern "C" void kernel_launch(void* const* d_in, const int* in_sizes, int n_in,
                              void* d_out, int out_size, void* d_ws, size_t ws_size,
                              hipStream_t stream) {
  const void* e0 = d_in[2];    // src_embedding_0 (6000x256)
  const void* e1 = d_in[3];    // src_embedding_1
  const void* gw = d_in[8];    // gnn_weight (256x256)
  const void* gb = d_in[9];    // gnn_bias (256)
  const void* aw = d_in[10];   // attn_weight (256)
  const void* abp = d_in[11];  // attn_bias (1)

  float* wsf = (float*)d_ws;   // offsets in 4-byte slots
  size_t o = 0;
  int*    flag  = (int*)(wsf + o); o += 4;
  u16*    ce    = (u16*)(wsf + o); o += 1536000;   // 12000x256 bf16 (written/used only for f32 inputs)
  u16*    cgwh  = (u16*)(wsf + o); o += 32768;     // 256x256 bf16
  float*  pgb   = wsf + o; o += 256;
  float*  paw   = wsf + o; o += 256;
  float*  pab   = wsf + o; o += 8;
  double* rinv64 = (double*)(wsf + o); o += 24000; // 12000 f64 (offset even -> 8B aligned)
  float*  rinv  = wsf + o; o += 12032;
  unsigned int* kbuf = (unsigned int*)(wsf + o); o += 768000;  // 12000 x 8ch x 8 packed keys
  u16*    xwb   = (u16*)(wsf + o); o += 1536000;   // 12000x256 bf16 -- SEPARATE (fused kernel
                                                   // writes kbuf and xwb concurrently; no overlay)
  int*    edst  = (int*)(wsf + o); o += 60000;
  int*    cnt   = (int*)(wsf + o); o += 12000;
  int*    fill  = (int*)(wsf + o); o += 12000;
  int*    coff  = (int*)(wsf + o); o += 12008;
  int*    cedge = (int*)(wsf + o); o += 60000;
  float*  macc  = wsf + o; o += 512;
  float*  dinv  = wsf + o; o += 12000;             // total ~16.3 MiB (<= r4's proven-live 18.9 MiB)
  (void)in_sizes; (void)n_in; (void)out_size; (void)ws_size;

  k_prep<<<3065, 256, 0, stream>>>(e0, e1, gw, gb, aw, abp, ce, cgwh, pgb, paw, pab,
                                   rinv, rinv64, cnt, fill, macc, flag);
  k_simxw<<<2256, 256, 0, stream>>>(e0, e1, ce, rinv, cgwh, flag, kbuf, xwb);
  k_rank<<<3000, 256, 0, stream>>>(e0, e1, kbuf, rinv64, flag, edst, cnt);
  k_scan<<<1, 1024, 0, stream>>>(cnt, coff, dinv);
  k_fill<<<235, 256, 0, stream>>>(edst, coff, fill, cedge);
  k_gather<<<750, 256, 0, stream>>>(e0, e1, xwb, dinv, coff, cedge, pgb, paw, pab, flag, d_out, macc);
  k_loss<<<1, 256, 0, stream>>>(macc, flag, d_out);
}